// Round 8
// baseline (102.274 us; speedup 1.0000x reference)
//
#include <hip/hip_runtime.h>
#include <hip/hip_bf16.h>
#include <math.h>

// Problem constants (fixed by setup_inputs)
#define EDGES   32768
#define NPTS    32768
#define IMGH    256
#define L0      32768
#define L1      16384
#define L2      8192
#define L3      4096
#define S0      (L1 + 64)    // Y0 row stride (padded)
#define NBC     133          // convBC blocks (31 outputs each)

// prep2 block ranges
#define PB_SCAN 128
#define PB_W    18
#define PB_T    1024
#define PREP_GRID (PB_SCAN + PB_W + PB_T + 128)   // 1298
#define K2_GRID   (256 + NBC)                     // 389

// ---------------------------------------------------------------------------
// device-scope produce/consume protocol (Guideline 16)
// ---------------------------------------------------------------------------
__device__ __forceinline__ void spin_until(unsigned* ctr, unsigned target, int tid)
{
    if (tid == 0) {
        while (__hip_atomic_load(ctr, __ATOMIC_ACQUIRE, __HIP_MEMORY_SCOPE_AGENT) < target)
            __builtin_amdgcn_s_sleep(2);
    }
    __syncthreads();
}
__device__ __forceinline__ void mark_done(unsigned* ctr, int tid)
{
    __syncthreads();                       // all block stores issued+drained
    if (tid == 0) {
        __threadfence();                   // flush to device scope
        __hip_atomic_fetch_add(ctr, 1u, __ATOMIC_RELEASE, __HIP_MEMORY_SCOPE_AGENT);
    }
}

// Batched weight-chunk staging: 96 rows x 64 ch = 1536 float4, 6 per thread.
__device__ __forceinline__ void stage_ws(float ws[96][64],
                                         const float* __restrict__ Wsrc, int tid)
{
    const float4* src = (const float4*)Wsrc;
    float4 rw[6];
#pragma unroll
    for (int k = 0; k < 6; ++k) rw[k] = src[k * 256 + tid];
    float4* dst = (float4*)&ws[0][0];
#pragma unroll
    for (int k = 0; k < 6; ++k) dst[k * 256 + tid] = rw[k];
}

// 64x64 k=3 stride-2 conv compute on a staged half.
__device__ __forceinline__ void conv_half(float acc[16],
                                          const float xs[64][130],
                                          const float ws[96][64],
                                          int ibase, int jl2, int o0)
{
#pragma unroll 4
    for (int ii = 0; ii < 32; ++ii) {
        int i = ibase + ii;
        float x0 = xs[i][jl2], x1 = xs[i][jl2 + 1], x2 = xs[i][jl2 + 2];
        const float4* w0 = (const float4*)&ws[ii*3 + 0][o0];
        const float4* w1 = (const float4*)&ws[ii*3 + 1][o0];
        const float4* w2 = (const float4*)&ws[ii*3 + 2][o0];
#pragma unroll
        for (int q = 0; q < 4; ++q) {
            float4 a = w0[q], b = w1[q], c = w2[q];
            acc[q*4+0] = fmaf(a.x, x0, fmaf(b.x, x1, fmaf(c.x, x2, acc[q*4+0])));
            acc[q*4+1] = fmaf(a.y, x0, fmaf(b.y, x1, fmaf(c.y, x2, acc[q*4+1])));
            acc[q*4+2] = fmaf(a.z, x0, fmaf(b.z, x1, fmaf(c.z, x2, acc[q*4+2])));
            acc[q*4+3] = fmaf(a.w, x0, fmaf(b.w, x1, fmaf(c.w, x2, acc[q*4+3])));
        }
    }
}

// ---------------------------------------------------------------------------
// Kernel 1 (prep2): scan | weights | transpose | point-search, one grid.
//   [0,128)     scan: 256 edges/block, f64 lengths + in-block scan -> el2loc,
//               partial; release scanDone.
//   [128,146)   weight transpose -> Wt.
//   [146,1170)  image transpose 64px/block, float4 in/out, ch 62/63 skipped.
//   [1170,1298) gather: spin scanDone==128, scan 128 partials, per-point
//               two-level search -> pts (px,py) + ridx (pixel row).
// ---------------------------------------------------------------------------
__global__ __launch_bounds__(256) void prep2_k(const float* __restrict__ corners,
                                               const float* __restrict__ W0,
                                               const float* __restrict__ W1,
                                               const float* __restrict__ W2,
                                               const float* __restrict__ img,
                                               double* __restrict__ el2loc,
                                               double* __restrict__ partial,
                                               float2* __restrict__ pts,
                                               int*    __restrict__ ridx,
                                               float*  __restrict__ Wt,
                                               float*  __restrict__ imgT,
                                               unsigned* __restrict__ ctr)
{
    __shared__ union {
        double sc[256];        // scan
        float  tt[64][68];     // transpose tile [pixel][channel]
        double sb[128];        // gather chunk offsets
    } sm;
    int b = blockIdx.x, t = threadIdx.x;

    if (b < PB_SCAN) {
        int e  = (b << 8) + t;
        int en = (e + 1) & (EDGES - 1);
        double dx = (double)corners[2*en]   - (double)corners[2*e];
        double dy = (double)corners[2*en+1] - (double)corners[2*e+1];
        sm.sc[t] = sqrt(dx*dx + dy*dy);
        __syncthreads();
        for (int o = 1; o < 256; o <<= 1) {        // Hillis-Steele inclusive
            double v = (t >= o) ? sm.sc[t - o] : 0.0;
            __syncthreads();
            sm.sc[t] += v;
            __syncthreads();
        }
        el2loc[e] = sm.sc[t];
        if (t == 255) partial[b] = sm.sc[255];
        mark_done(&ctr[0], t);
    } else if (b < PB_SCAN + PB_W) {
        int wb = b - PB_SCAN;
#pragma unroll
        for (int k = 0; k < 8; ++k) {
            int idx = wb*2048 + k*256 + t;         // < 36864 exactly
            int l   = idx / 12288;
            int rem = idx - l * 12288;
            int row = rem >> 6, o = rem & 63;
            int i   = row / 3,  kk = row - i * 3;
            const float* W = (l == 0) ? W0 : ((l == 1) ? W1 : W2);
            Wt[idx] = W[o*192 + i*3 + kk];
        }
    } else if (b < PB_SCAN + PB_W + PB_T) {
        int tb   = b - (PB_SCAN + PB_W);
        int pix0 = tb << 6;                        // 64 pixels/block
        const float4* img4 = (const float4*)img;
#pragma unroll
        for (int k = 0; k < 4; ++k) {
            int idx = k*256 + t;
            if (idx < 992) {                       // 62 ch x 16 float4
                int c = idx >> 4, p4 = idx & 15;
                float4 v = img4[c*16384 + (pix0 >> 2) + p4];
                sm.tt[p4*4 + 0][c] = v.x;
                sm.tt[p4*4 + 1][c] = v.y;
                sm.tt[p4*4 + 2][c] = v.z;
                sm.tt[p4*4 + 3][c] = v.w;
            }
        }
        __syncthreads();
        float4* imgT4 = (float4*)imgT;
#pragma unroll
        for (int k = 0; k < 4; ++k) {
            int idx = k*256 + t;                   // < 1024
            int p = idx >> 4, c4 = idx & 15;
            if (c4 < 15) {
                float4 v = *(const float4*)&sm.tt[p][c4*4];
                imgT4[((size_t)(pix0 + p) << 4) + c4] = v;
            } else {                               // channels 60,61; 62/63 unused
                float2 v = make_float2(sm.tt[p][60], sm.tt[p][61]);
                *(float2*)(imgT + ((size_t)(pix0 + p) << 6) + 60) = v;
            }
        }
    } else {
        int gb = b - (PB_SCAN + PB_W + PB_T);
        spin_until(&ctr[0], PB_SCAN, t);
        if (t < 128) sm.sb[t] = partial[t];
        __syncthreads();
        for (int o = 1; o < 128; o <<= 1) {
            double v = 0.0;
            if (t < 128 && t >= o) v = sm.sb[t - o];
            __syncthreads();
            if (t < 128) sm.sb[t] += v;
            __syncthreads();
        }
        int p = (gb << 8) + t;
        double S   = sm.sb[127];
        double off = (double)p * (S * (1.0 / (double)NPTS));
        // two-level lower_bound: chunk via sb (LDS), then 256-edge chunk.
        int clo = 0, chi = 127;
        while (clo < chi) { int cm = (clo + chi) >> 1;
                            if (sm.sb[cm] > off) chi = cm; else clo = cm + 1; }
        double base = clo ? sm.sb[clo - 1] : 0.0;
        int lo = clo << 8, hi = lo + 255;
        while (lo < hi) { int mid = (lo + hi) >> 1;
                          if (el2loc[mid] + base > off) hi = mid; else lo = mid + 1; }
        int e = lo;
        double e1 = (e == 0) ? 0.0
                  : el2loc[e-1] + (((e-1) >= 256) ? sm.sb[((e-1) >> 8) - 1] : 0.0);
        float sxf = corners[2*e], syf = corners[2*e+1];
        int en = (e + 1) & (EDGES - 1);
        double dx = (double)corners[2*en]   - (double)sxf;
        double dy = (double)corners[2*en+1] - (double)syf;
        double len = sqrt(dx*dx + dy*dy);
        double tp  = (off - e1) / fmax(len, 0.0001);
        double px  = (double)sxf + tp * dx;
        double py  = (double)syf + tp * dy;
        int r0 = (int)rint(px * (double)IMGH); r0 = r0 < 0 ? 0 : (r0 > IMGH-1 ? IMGH-1 : r0);
        int r1 = (int)rint(py * (double)IMGH); r1 = r1 < 0 ? 0 : (r1 > IMGH-1 ? IMGH-1 : r1);
        pts[p]  = make_float2((float)px, (float)py);
        ridx[p] = (r0 << 8) | r1;
    }
}

// ---------------------------------------------------------------------------
// Kernel 2 (conv): convA [0,256) | convBC+fc [256,389), one grid, spin-linked.
// ---------------------------------------------------------------------------
__global__ __launch_bounds__(256) void conv_k(const float2* __restrict__ pts,
                                              const int*    __restrict__ ridx,
                                              const float*  __restrict__ imgT,
                                              const float*  __restrict__ Wt,
                                              const float*  __restrict__ b0v,
                                              const float*  __restrict__ b1v,
                                              const float*  __restrict__ b2v,
                                              const float*  __restrict__ Wf,
                                              const float*  __restrict__ bf,
                                              const float*  __restrict__ Wp,
                                              const float*  __restrict__ bp,
                                              float* __restrict__ Y0,
                                              float* __restrict__ pmax,
                                              unsigned* __restrict__ ctr,
                                              float* __restrict__ out)
{
    __shared__ union {
        struct { float xs[64][130]; float ws[96][64]; } a;                  // 57856 B
        struct { float xs0[32][132]; float t1[64][63]; float ws[96][64];
                 float cm[64]; float ft[64]; unsigned tick; } bc;           // 58116 B
    } u;
    int tid = threadIdx.x;
    int b   = blockIdx.x;

    if (b < 256) {
        // ================= convA: gather + conv layer 0 =================
        int j0  = b << 6;
        int in0 = (j0 << 1) - 1;
        stage_ws(u.a.ws, Wt, tid);                 // W0 chunk 0
        if (tid < 130) {
            int g = in0 + tid;
            if (g < 0)   g = 1;                    // reflect left
            if (g >= L0) g = 2*L0 - 2 - g;         // halo guard
            float2 pxy = pts[g];
            int    rid = ridx[g];
            const float4* row4 = (const float4*)(imgT + ((size_t)rid << 6));
            float4 rv[15];
#pragma unroll
            for (int c4 = 0; c4 < 15; ++c4) rv[c4] = row4[c4];
            float c60 = ((const float*)row4)[60], c61 = ((const float*)row4)[61];
#pragma unroll
            for (int c4 = 0; c4 < 15; ++c4) {
                u.a.xs[c4*4 + 0][tid] = rv[c4].x;
                u.a.xs[c4*4 + 1][tid] = rv[c4].y;
                u.a.xs[c4*4 + 2][tid] = rv[c4].z;
                u.a.xs[c4*4 + 3][tid] = rv[c4].w;
            }
            u.a.xs[60][tid] = c60;
            u.a.xs[61][tid] = c61;
            u.a.xs[62][tid] = pxy.x;
            u.a.xs[63][tid] = pxy.y;
        }
        __syncthreads();

        int lane = tid & 63;
        int o0   = (tid >> 6) << 4;
        float acc[16];
#pragma unroll
        for (int m = 0; m < 16; ++m) acc[m] = b0v[o0 + m];
        int jl2 = lane << 1;

        conv_half(acc, u.a.xs, u.a.ws, 0, jl2, o0);
        __syncthreads();
        stage_ws(u.a.ws, Wt + 96*64, tid);         // W0 chunk 1
        __syncthreads();
        conv_half(acc, u.a.xs, u.a.ws, 32, jl2, o0);

        int j = j0 + lane;
#pragma unroll
        for (int m = 0; m < 16; ++m)
            Y0[(o0 + m) * S0 + j] = fmaxf(acc[m], 0.f);
        mark_done(&ctr[1], tid);
    } else {
        // ============ convBC: conv1+conv2 fused + maxpool + fc ============
        int bb = b - 256;
        int gbase = 124*bb - 3;
        stage_ws(u.bc.ws, Wt + 12288, tid);        // W1 chunk 0 (pre-spin)
        spin_until(&ctr[1], 256, tid);             // wait all convA blocks

        int s  = tid & 63;
        int o0 = (tid >> 6) << 4;
        int j1 = 62*bb - 1 + s;
        int jr = (j1 < 0) ? -j1 : (j1 > L2-1 ? L2-1 : j1);
        int col0 = 2*jr - 124*bb + 2;

        {   // stage Y0 half-0 (in-ch 0..31)
            float r[16];
#pragma unroll
            for (int k = 0; k < 16; ++k) {
                int idx = k*256 + tid;
                int c   = idx >> 7, col = idx & 127;
                int g   = gbase + col;
                if (g < 0)   g = -g;
                if (g >= L1) g = 2*L1 - 2 - g;
                r[k] = Y0[c * S0 + g];
            }
#pragma unroll
            for (int k = 0; k < 16; ++k) {
                int idx = k*256 + tid;
                u.bc.xs0[idx >> 7][idx & 127] = r[k];
            }
        }
        __syncthreads();

        float acc1[16];
#pragma unroll
        for (int m = 0; m < 16; ++m) acc1[m] = b1v[o0 + m];
#pragma unroll 4
        for (int ii = 0; ii < 32; ++ii) {
            float x0 = u.bc.xs0[ii][col0], x1 = u.bc.xs0[ii][col0+1], x2 = u.bc.xs0[ii][col0+2];
            const float4* w0 = (const float4*)&u.bc.ws[ii*3 + 0][o0];
            const float4* w1 = (const float4*)&u.bc.ws[ii*3 + 1][o0];
            const float4* w2 = (const float4*)&u.bc.ws[ii*3 + 2][o0];
#pragma unroll
            for (int q = 0; q < 4; ++q) {
                float4 a = w0[q], bw = w1[q], c = w2[q];
                acc1[q*4+0] = fmaf(a.x, x0, fmaf(bw.x, x1, fmaf(c.x, x2, acc1[q*4+0])));
                acc1[q*4+1] = fmaf(a.y, x0, fmaf(bw.y, x1, fmaf(c.y, x2, acc1[q*4+1])));
                acc1[q*4+2] = fmaf(a.z, x0, fmaf(bw.z, x1, fmaf(c.z, x2, acc1[q*4+2])));
                acc1[q*4+3] = fmaf(a.w, x0, fmaf(bw.w, x1, fmaf(c.w, x2, acc1[q*4+3])));
            }
        }
        __syncthreads();
        {   // stage Y0 half-1 (in-ch 32..63) + W1 chunk 1
            float r[16];
#pragma unroll
            for (int k = 0; k < 16; ++k) {
                int idx = k*256 + tid;
                int c   = idx >> 7, col = idx & 127;
                int g   = gbase + col;
                if (g < 0)   g = -g;
                if (g >= L1) g = 2*L1 - 2 - g;
                r[k] = Y0[(32 + c) * S0 + g];
            }
            stage_ws(u.bc.ws, Wt + 12288 + 96*64, tid);
#pragma unroll
            for (int k = 0; k < 16; ++k) {
                int idx = k*256 + tid;
                u.bc.xs0[idx >> 7][idx & 127] = r[k];
            }
        }
        __syncthreads();
#pragma unroll 4
        for (int ii = 0; ii < 32; ++ii) {
            float x0 = u.bc.xs0[ii][col0], x1 = u.bc.xs0[ii][col0+1], x2 = u.bc.xs0[ii][col0+2];
            const float4* w0 = (const float4*)&u.bc.ws[ii*3 + 0][o0];
            const float4* w1 = (const float4*)&u.bc.ws[ii*3 + 1][o0];
            const float4* w2 = (const float4*)&u.bc.ws[ii*3 + 2][o0];
#pragma unroll
            for (int q = 0; q < 4; ++q) {
                float4 a = w0[q], bw = w1[q], c = w2[q];
                acc1[q*4+0] = fmaf(a.x, x0, fmaf(bw.x, x1, fmaf(c.x, x2, acc1[q*4+0])));
                acc1[q*4+1] = fmaf(a.y, x0, fmaf(bw.y, x1, fmaf(c.y, x2, acc1[q*4+1])));
                acc1[q*4+2] = fmaf(a.z, x0, fmaf(bw.z, x1, fmaf(c.z, x2, acc1[q*4+2])));
                acc1[q*4+3] = fmaf(a.w, x0, fmaf(bw.w, x1, fmaf(c.w, x2, acc1[q*4+3])));
            }
        }
        __syncthreads();
        if (s < 63) {
#pragma unroll
            for (int m = 0; m < 16; ++m) u.bc.t1[o0 + m][s] = fmaxf(acc1[m], 0.f);
        }
        __syncthreads();

        // conv2: thread -> (pos p, 8-ch group)
        int p  = tid & 31;
        int oc = (tid >> 5) << 3;
        float acc2[8];
#pragma unroll
        for (int q = 0; q < 8; ++q) acc2[q] = b2v[oc + q];

        stage_ws(u.bc.ws, Wt + 24576, tid);        // W2 chunk 0
        __syncthreads();
#pragma unroll 4
        for (int ii = 0; ii < 32; ++ii) {
            float x0 = u.bc.t1[ii][2*p + 0], x1 = u.bc.t1[ii][2*p + 1], x2 = u.bc.t1[ii][2*p + 2];
            const float4* w0 = (const float4*)&u.bc.ws[ii*3 + 0][oc];
            const float4* w1 = (const float4*)&u.bc.ws[ii*3 + 1][oc];
            const float4* w2 = (const float4*)&u.bc.ws[ii*3 + 2][oc];
#pragma unroll
            for (int q4 = 0; q4 < 2; ++q4) {
                float4 a = w0[q4], bw = w1[q4], c = w2[q4];
                acc2[q4*4+0] = fmaf(a.x, x0, fmaf(bw.x, x1, fmaf(c.x, x2, acc2[q4*4+0])));
                acc2[q4*4+1] = fmaf(a.y, x0, fmaf(bw.y, x1, fmaf(c.y, x2, acc2[q4*4+1])));
                acc2[q4*4+2] = fmaf(a.z, x0, fmaf(bw.z, x1, fmaf(c.z, x2, acc2[q4*4+2])));
                acc2[q4*4+3] = fmaf(a.w, x0, fmaf(bw.w, x1, fmaf(c.w, x2, acc2[q4*4+3])));
            }
        }
        __syncthreads();
        stage_ws(u.bc.ws, Wt + 24576 + 96*64, tid);   // W2 chunk 1
        __syncthreads();
#pragma unroll 4
        for (int ii = 0; ii < 32; ++ii) {
            float x0 = u.bc.t1[32+ii][2*p + 0], x1 = u.bc.t1[32+ii][2*p + 1], x2 = u.bc.t1[32+ii][2*p + 2];
            const float4* w0 = (const float4*)&u.bc.ws[ii*3 + 0][oc];
            const float4* w1 = (const float4*)&u.bc.ws[ii*3 + 1][oc];
            const float4* w2 = (const float4*)&u.bc.ws[ii*3 + 2][oc];
#pragma unroll
            for (int q4 = 0; q4 < 2; ++q4) {
                float4 a = w0[q4], bw = w1[q4], c = w2[q4];
                acc2[q4*4+0] = fmaf(a.x, x0, fmaf(bw.x, x1, fmaf(c.x, x2, acc2[q4*4+0])));
                acc2[q4*4+1] = fmaf(a.y, x0, fmaf(bw.y, x1, fmaf(c.y, x2, acc2[q4*4+1])));
                acc2[q4*4+2] = fmaf(a.z, x0, fmaf(bw.z, x1, fmaf(c.z, x2, acc2[q4*4+2])));
                acc2[q4*4+3] = fmaf(a.w, x0, fmaf(bw.w, x1, fmaf(c.w, x2, acc2[q4*4+3])));
            }
        }

        bool valid = (p < 31) && (31*bb + p < L3);
#pragma unroll
        for (int q = 0; q < 8; ++q) {
            float v = valid ? fmaxf(acc2[q], 0.f) : 0.f;
#pragma unroll
            for (int off = 1; off < 32; off <<= 1)
                v = fmaxf(v, __shfl_xor(v, off));
            if (p == 0) pmax[bb * 64 + oc + q] = v;
        }
        __syncthreads();
        if (tid == 0) {
            __threadfence();
            u.bc.tick = __hip_atomic_fetch_add(&ctr[2], 1u, __ATOMIC_ACQ_REL,
                                               __HIP_MEMORY_SCOPE_AGENT);
        }
        __syncthreads();
        if (u.bc.tick == NBC - 1) {                // last block: maxes + FCs
            __threadfence();
            if (tid < 64) {
                float m = 0.f;
#pragma unroll
                for (int q = 0; q < NBC; ++q) m = fmaxf(m, pmax[q * 64 + tid]);
                u.bc.cm[tid] = m;
            }
            __syncthreads();
            if (tid < 64) {
                float sfc = bf[tid];
#pragma unroll
                for (int c = 0; c < 64; ++c) sfc = fmaf(Wf[tid*64 + c], u.bc.cm[c], sfc);
                float f = fmaxf(sfc, 0.f);
                u.bc.ft[tid] = f;
                out[tid] = f;
            }
            __syncthreads();
            if (tid == 0) {
                float z = bp[0];
#pragma unroll
                for (int c = 0; c < 64; ++c) z = fmaf(Wp[c], u.bc.ft[c], z);
                out[64] = 1.f / (1.f + expf(-z));
            }
        }
    }
}

// ---------------------------------------------------------------------------
extern "C" void kernel_launch(void* const* d_in, const int* in_sizes, int n_in,
                              void* d_out, int out_size, void* d_ws, size_t ws_size,
                              hipStream_t stream)
{
    const float* image   = (const float*)d_in[0];
    const float* corners = (const float*)d_in[1];
    const float* W0      = (const float*)d_in[2];
    const float* b0      = (const float*)d_in[3];
    const float* W1      = (const float*)d_in[4];
    const float* b1      = (const float*)d_in[5];
    const float* W2      = (const float*)d_in[6];
    const float* b2      = (const float*)d_in[7];
    const float* Wf      = (const float*)d_in[8];
    const float* bf      = (const float*)d_in[9];
    const float* Wp      = (const float*)d_in[10];
    const float* bp      = (const float*)d_in[11];
    float* out = (float*)d_out;

    // workspace layout (256B-aligned), ~21.8 MB used
    char* w = (char*)d_ws;
    unsigned* ctr     = (unsigned*)(w);              //      256 B
    double*   el2loc  = (double*)  (w + 256);        //   262144 B
    double*   partial = (double*)  (w + 262400);     //     1024 B
    float2*   pts     = (float2*)  (w + 263424);     //   262144 B
    int*      ridx    = (int*)     (w + 525568);     //   131072 B
    float*    pmax    = (float*)   (w + 656640);     //    34048 B
    float*    Wt      = (float*)   (w + 690688);     //   147456 B
    float*    imgT    = (float*)   (w + 838144);     // 16777216 B
    float*    Y0      = (float*)   (w + 17615360);   //  4210688 B -> 21826048

    hipMemsetAsync(ctr, 0, 256, stream);
    prep2_k <<<PREP_GRID, 256, 0, stream>>>(corners, W0, W1, W2, image,
                                            el2loc, partial, pts, ridx, Wt, imgT, ctr);
    conv_k  <<<K2_GRID, 256, 0, stream>>>(pts, ridx, imgT, Wt, b0, b1, b2,
                                          Wf, bf, Wp, bp, Y0, pmax, ctr, out);
}

// Round 9
// 74.855 us; speedup vs baseline: 1.3663x; 1.3663x over previous
//
#include <hip/hip_runtime.h>
#include <hip/hip_bf16.h>
#include <math.h>

// Problem constants (fixed by setup_inputs)
#define EDGES   32768
#define NPTS    32768
#define IMGH    256
#define L0      32768
#define L1      16384
#define L2      8192
#define L3      4096
#define S0      (L1 + 64)    // Y0 row stride (padded)
#define NBC     133          // convBC blocks (31 outputs each)

// prep2 block ranges
#define PB_SCAN 128
#define PB_W    18
#define PB_T    1024
#define PREP_GRID (PB_SCAN + PB_W + PB_T + 128)   // 1298

// ---------------------------------------------------------------------------
// device-scope produce/consume (only used INSIDE prep2, where waiter blocks
// are dispatched after producers — R8 showed this pattern is ~free there,
// while cross-phase spins in a compute kernel caused an invalidation storm).
// ---------------------------------------------------------------------------
__device__ __forceinline__ void spin_until(unsigned* ctr, unsigned target, int tid)
{
    if (tid == 0) {
        while (__hip_atomic_load(ctr, __ATOMIC_ACQUIRE, __HIP_MEMORY_SCOPE_AGENT) < target)
            __builtin_amdgcn_s_sleep(2);
    }
    __syncthreads();
}
__device__ __forceinline__ void mark_done(unsigned* ctr, int tid)
{
    __syncthreads();
    if (tid == 0) {
        __threadfence();
        __hip_atomic_fetch_add(ctr, 1u, __ATOMIC_RELEASE, __HIP_MEMORY_SCOPE_AGENT);
    }
}

// Batched weight-chunk staging: 96 rows x 64 ch = 1536 float4, 6 per thread.
__device__ __forceinline__ void stage_ws(float ws[96][64],
                                         const float* __restrict__ Wsrc, int tid)
{
    const float4* src = (const float4*)Wsrc;
    float4 rw[6];
#pragma unroll
    for (int k = 0; k < 6; ++k) rw[k] = src[k * 256 + tid];
    float4* dst = (float4*)&ws[0][0];
#pragma unroll
    for (int k = 0; k < 6; ++k) dst[k * 256 + tid] = rw[k];
}

// 64x64 k=3 stride-2 conv compute on a staged half.
__device__ __forceinline__ void conv_half(float acc[16],
                                          const float xs[64][130],
                                          const float ws[96][64],
                                          int ibase, int jl2, int o0)
{
#pragma unroll 4
    for (int ii = 0; ii < 32; ++ii) {
        int i = ibase + ii;
        float x0 = xs[i][jl2], x1 = xs[i][jl2 + 1], x2 = xs[i][jl2 + 2];
        const float4* w0 = (const float4*)&ws[ii*3 + 0][o0];
        const float4* w1 = (const float4*)&ws[ii*3 + 1][o0];
        const float4* w2 = (const float4*)&ws[ii*3 + 2][o0];
#pragma unroll
        for (int q = 0; q < 4; ++q) {
            float4 a = w0[q], b = w1[q], c = w2[q];
            acc[q*4+0] = fmaf(a.x, x0, fmaf(b.x, x1, fmaf(c.x, x2, acc[q*4+0])));
            acc[q*4+1] = fmaf(a.y, x0, fmaf(b.y, x1, fmaf(c.y, x2, acc[q*4+1])));
            acc[q*4+2] = fmaf(a.z, x0, fmaf(b.z, x1, fmaf(c.z, x2, acc[q*4+2])));
            acc[q*4+3] = fmaf(a.w, x0, fmaf(b.w, x1, fmaf(c.w, x2, acc[q*4+3])));
        }
    }
}

// ---------------------------------------------------------------------------
// Kernel 1 (prep2): scan | weights | transpose | point-search, one grid.
// (R8-proven, ~3 us total)
// ---------------------------------------------------------------------------
__global__ __launch_bounds__(256) void prep2_k(const float* __restrict__ corners,
                                               const float* __restrict__ W0,
                                               const float* __restrict__ W1,
                                               const float* __restrict__ W2,
                                               const float* __restrict__ img,
                                               double* __restrict__ el2loc,
                                               double* __restrict__ partial,
                                               float2* __restrict__ pts,
                                               int*    __restrict__ ridx,
                                               float*  __restrict__ Wt,
                                               float*  __restrict__ imgT,
                                               unsigned* __restrict__ ctr)
{
    __shared__ union {
        double sc[256];        // scan
        float  tt[64][68];     // transpose tile [pixel][channel]
        double sb[128];        // gather chunk offsets
    } sm;
    int b = blockIdx.x, t = threadIdx.x;

    if (b < PB_SCAN) {
        int e  = (b << 8) + t;
        int en = (e + 1) & (EDGES - 1);
        double dx = (double)corners[2*en]   - (double)corners[2*e];
        double dy = (double)corners[2*en+1] - (double)corners[2*e+1];
        sm.sc[t] = sqrt(dx*dx + dy*dy);
        __syncthreads();
        for (int o = 1; o < 256; o <<= 1) {        // Hillis-Steele inclusive
            double v = (t >= o) ? sm.sc[t - o] : 0.0;
            __syncthreads();
            sm.sc[t] += v;
            __syncthreads();
        }
        el2loc[e] = sm.sc[t];
        if (t == 255) partial[b] = sm.sc[255];
        mark_done(&ctr[0], t);
    } else if (b < PB_SCAN + PB_W) {
        int wb = b - PB_SCAN;
#pragma unroll
        for (int k = 0; k < 8; ++k) {
            int idx = wb*2048 + k*256 + t;         // < 36864 exactly
            int l   = idx / 12288;
            int rem = idx - l * 12288;
            int row = rem >> 6, o = rem & 63;
            int i   = row / 3,  kk = row - i * 3;
            const float* W = (l == 0) ? W0 : ((l == 1) ? W1 : W2);
            Wt[idx] = W[o*192 + i*3 + kk];
        }
    } else if (b < PB_SCAN + PB_W + PB_T) {
        int tb   = b - (PB_SCAN + PB_W);
        int pix0 = tb << 6;                        // 64 pixels/block
        const float4* img4 = (const float4*)img;
#pragma unroll
        for (int k = 0; k < 4; ++k) {
            int idx = k*256 + t;
            if (idx < 992) {                       // 62 ch x 16 float4
                int c = idx >> 4, p4 = idx & 15;
                float4 v = img4[c*16384 + (pix0 >> 2) + p4];
                sm.tt[p4*4 + 0][c] = v.x;
                sm.tt[p4*4 + 1][c] = v.y;
                sm.tt[p4*4 + 2][c] = v.z;
                sm.tt[p4*4 + 3][c] = v.w;
            }
        }
        __syncthreads();
        float4* imgT4 = (float4*)imgT;
#pragma unroll
        for (int k = 0; k < 4; ++k) {
            int idx = k*256 + t;                   // < 1024
            int p = idx >> 4, c4 = idx & 15;
            if (c4 < 15) {
                float4 v = *(const float4*)&sm.tt[p][c4*4];
                imgT4[((size_t)(pix0 + p) << 4) + c4] = v;
            } else {                               // channels 60,61 (62/63 unused)
                float2 v = make_float2(sm.tt[p][60], sm.tt[p][61]);
                *(float2*)(imgT + ((size_t)(pix0 + p) << 6) + 60) = v;
            }
        }
    } else {
        int gb = b - (PB_SCAN + PB_W + PB_T);
        spin_until(&ctr[0], PB_SCAN, t);           // producers dispatched earlier
        if (t < 128) sm.sb[t] = partial[t];
        __syncthreads();
        for (int o = 1; o < 128; o <<= 1) {
            double v = 0.0;
            if (t < 128 && t >= o) v = sm.sb[t - o];
            __syncthreads();
            if (t < 128) sm.sb[t] += v;
            __syncthreads();
        }
        int p = (gb << 8) + t;
        double S   = sm.sb[127];
        double off = (double)p * (S * (1.0 / (double)NPTS));
        int clo = 0, chi = 127;
        while (clo < chi) { int cm = (clo + chi) >> 1;
                            if (sm.sb[cm] > off) chi = cm; else clo = cm + 1; }
        double base = clo ? sm.sb[clo - 1] : 0.0;
        int lo = clo << 8, hi = lo + 255;
        while (lo < hi) { int mid = (lo + hi) >> 1;
                          if (el2loc[mid] + base > off) hi = mid; else lo = mid + 1; }
        int e = lo;
        double e1 = (e == 0) ? 0.0
                  : el2loc[e-1] + (((e-1) >= 256) ? sm.sb[((e-1) >> 8) - 1] : 0.0);
        float sxf = corners[2*e], syf = corners[2*e+1];
        int en = (e + 1) & (EDGES - 1);
        double dx = (double)corners[2*en]   - (double)sxf;
        double dy = (double)corners[2*en+1] - (double)syf;
        double len = sqrt(dx*dx + dy*dy);
        double tp  = (off - e1) / fmax(len, 0.0001);
        double px  = (double)sxf + tp * dx;
        double py  = (double)syf + tp * dy;
        int r0 = (int)rint(px * (double)IMGH); r0 = r0 < 0 ? 0 : (r0 > IMGH-1 ? IMGH-1 : r0);
        int r1 = (int)rint(py * (double)IMGH); r1 = r1 < 0 ? 0 : (r1 > IMGH-1 ? IMGH-1 : r1);
        pts[p]  = make_float2((float)px, (float)py);
        ridx[p] = (r0 << 8) | r1;
    }
}

// ---------------------------------------------------------------------------
// Kernel 2 (convA2): gather (precomputed pts/ridx) + conv layer 0 -> Y0.
// Spin-free.
// ---------------------------------------------------------------------------
__global__ __launch_bounds__(256) void convA2_k(const float2* __restrict__ pts,
                                                const int*    __restrict__ ridx,
                                                const float*  __restrict__ imgT,
                                                const float*  __restrict__ Wt,
                                                const float*  __restrict__ b0v,
                                                float* __restrict__ Y0)
{
    __shared__ float xs[64][130];   // 33280 B
    __shared__ float ws[96][64];    // 24576 B
    int tid = threadIdx.x;
    int b   = blockIdx.x;
    int j0  = b << 6;
    int in0 = (j0 << 1) - 1;

    stage_ws(ws, Wt, tid);                         // W0 chunk 0
    if (tid < 130) {
        int g = in0 + tid;
        if (g < 0)   g = 1;                        // reflect left
        if (g >= L0) g = 2*L0 - 2 - g;             // halo guard
        float2 pxy = pts[g];
        int    rid = ridx[g];
        const float4* row4 = (const float4*)(imgT + ((size_t)rid << 6));
        float4 rv[15];
#pragma unroll
        for (int c4 = 0; c4 < 15; ++c4) rv[c4] = row4[c4];
        float c60 = ((const float*)row4)[60], c61 = ((const float*)row4)[61];
#pragma unroll
        for (int c4 = 0; c4 < 15; ++c4) {
            xs[c4*4 + 0][tid] = rv[c4].x;
            xs[c4*4 + 1][tid] = rv[c4].y;
            xs[c4*4 + 2][tid] = rv[c4].z;
            xs[c4*4 + 3][tid] = rv[c4].w;
        }
        xs[60][tid] = c60;
        xs[61][tid] = c61;
        xs[62][tid] = pxy.x;
        xs[63][tid] = pxy.y;
    }
    __syncthreads();

    int lane = tid & 63;
    int o0   = (tid >> 6) << 4;
    float acc[16];
#pragma unroll
    for (int m = 0; m < 16; ++m) acc[m] = b0v[o0 + m];
    int jl2 = lane << 1;

    conv_half(acc, xs, ws, 0, jl2, o0);
    __syncthreads();
    stage_ws(ws, Wt + 96*64, tid);                 // W0 chunk 1
    __syncthreads();
    conv_half(acc, xs, ws, 32, jl2, o0);

    int j = j0 + lane;
#pragma unroll
    for (int m = 0; m < 16; ++m)
        Y0[(o0 + m) * S0 + j] = fmaxf(acc[m], 0.f);
}

// ---------------------------------------------------------------------------
// Kernel 3 (convBC): conv1 + conv2 fused; Y1 never materialized. (R7-proven)
// ---------------------------------------------------------------------------
__global__ __launch_bounds__(256) void convBC_k(const float* __restrict__ Y0,
                                                const float* __restrict__ Wt1,
                                                const float* __restrict__ b1,
                                                const float* __restrict__ Wt2,
                                                const float* __restrict__ b2,
                                                float* __restrict__ pmax)
{
    __shared__ float xs0[32][132];   // 16896 B
    __shared__ float t1[64][63];     // 16128 B
    __shared__ float ws[96][64];     // 24576 B
    int tid = threadIdx.x;
    int b   = blockIdx.x;
    int gbase = 124*b - 3;

    int s  = tid & 63;
    int o0 = (tid >> 6) << 4;
    int j1 = 62*b - 1 + s;
    int jr = (j1 < 0) ? -j1 : (j1 > L2-1 ? L2-1 : j1);
    int col0 = 2*jr - 124*b + 2;

    {   // stage Y0 half-0 (in-ch 0..31) + W1 chunk0
        float r[16];
#pragma unroll
        for (int k = 0; k < 16; ++k) {
            int idx = k*256 + tid;
            int c   = idx >> 7, col = idx & 127;
            int g   = gbase + col;
            if (g < 0)   g = -g;
            if (g >= L1) g = 2*L1 - 2 - g;
            r[k] = Y0[c * S0 + g];
        }
        stage_ws(ws, Wt1, tid);
#pragma unroll
        for (int k = 0; k < 16; ++k) {
            int idx = k*256 + tid;
            xs0[idx >> 7][idx & 127] = r[k];
        }
    }
    __syncthreads();

    float acc1[16];
#pragma unroll
    for (int m = 0; m < 16; ++m) acc1[m] = b1[o0 + m];
#pragma unroll 4
    for (int ii = 0; ii < 32; ++ii) {
        float x0 = xs0[ii][col0], x1 = xs0[ii][col0+1], x2 = xs0[ii][col0+2];
        const float4* w0 = (const float4*)&ws[ii*3 + 0][o0];
        const float4* w1 = (const float4*)&ws[ii*3 + 1][o0];
        const float4* w2 = (const float4*)&ws[ii*3 + 2][o0];
#pragma unroll
        for (int q = 0; q < 4; ++q) {
            float4 a = w0[q], bb = w1[q], c = w2[q];
            acc1[q*4+0] = fmaf(a.x, x0, fmaf(bb.x, x1, fmaf(c.x, x2, acc1[q*4+0])));
            acc1[q*4+1] = fmaf(a.y, x0, fmaf(bb.y, x1, fmaf(c.y, x2, acc1[q*4+1])));
            acc1[q*4+2] = fmaf(a.z, x0, fmaf(bb.z, x1, fmaf(c.z, x2, acc1[q*4+2])));
            acc1[q*4+3] = fmaf(a.w, x0, fmaf(bb.w, x1, fmaf(c.w, x2, acc1[q*4+3])));
        }
    }
    __syncthreads();
    {   // stage Y0 half-1 (in-ch 32..63) + W1 chunk1
        float r[16];
#pragma unroll
        for (int k = 0; k < 16; ++k) {
            int idx = k*256 + tid;
            int c   = idx >> 7, col = idx & 127;
            int g   = gbase + col;
            if (g < 0)   g = -g;
            if (g >= L1) g = 2*L1 - 2 - g;
            r[k] = Y0[(32 + c) * S0 + g];
        }
        stage_ws(ws, Wt1 + 96*64, tid);
#pragma unroll
        for (int k = 0; k < 16; ++k) {
            int idx = k*256 + tid;
            xs0[idx >> 7][idx & 127] = r[k];
        }
    }
    __syncthreads();
#pragma unroll 4
    for (int ii = 0; ii < 32; ++ii) {
        float x0 = xs0[ii][col0], x1 = xs0[ii][col0+1], x2 = xs0[ii][col0+2];
        const float4* w0 = (const float4*)&ws[ii*3 + 0][o0];
        const float4* w1 = (const float4*)&ws[ii*3 + 1][o0];
        const float4* w2 = (const float4*)&ws[ii*3 + 2][o0];
#pragma unroll
        for (int q = 0; q < 4; ++q) {
            float4 a = w0[q], bb = w1[q], c = w2[q];
            acc1[q*4+0] = fmaf(a.x, x0, fmaf(bb.x, x1, fmaf(c.x, x2, acc1[q*4+0])));
            acc1[q*4+1] = fmaf(a.y, x0, fmaf(bb.y, x1, fmaf(c.y, x2, acc1[q*4+1])));
            acc1[q*4+2] = fmaf(a.z, x0, fmaf(bb.z, x1, fmaf(c.z, x2, acc1[q*4+2])));
            acc1[q*4+3] = fmaf(a.w, x0, fmaf(bb.w, x1, fmaf(c.w, x2, acc1[q*4+3])));
        }
    }
    __syncthreads();
    if (s < 63) {
#pragma unroll
        for (int m = 0; m < 16; ++m) t1[o0 + m][s] = fmaxf(acc1[m], 0.f);
    }
    __syncthreads();

    // conv2: thread -> (pos p, 8-ch group)
    int p  = tid & 31;
    int oc = (tid >> 5) << 3;
    float acc2[8];
#pragma unroll
    for (int q = 0; q < 8; ++q) acc2[q] = b2[oc + q];

    stage_ws(ws, Wt2, tid);              // W2 chunk0
    __syncthreads();
#pragma unroll 4
    for (int ii = 0; ii < 32; ++ii) {
        float x0 = t1[ii][2*p + 0], x1 = t1[ii][2*p + 1], x2 = t1[ii][2*p + 2];
        const float4* w0 = (const float4*)&ws[ii*3 + 0][oc];
        const float4* w1 = (const float4*)&ws[ii*3 + 1][oc];
        const float4* w2 = (const float4*)&ws[ii*3 + 2][oc];
#pragma unroll
        for (int q4 = 0; q4 < 2; ++q4) {
            float4 a = w0[q4], bb = w1[q4], c = w2[q4];
            acc2[q4*4+0] = fmaf(a.x, x0, fmaf(bb.x, x1, fmaf(c.x, x2, acc2[q4*4+0])));
            acc2[q4*4+1] = fmaf(a.y, x0, fmaf(bb.y, x1, fmaf(c.y, x2, acc2[q4*4+1])));
            acc2[q4*4+2] = fmaf(a.z, x0, fmaf(bb.z, x1, fmaf(c.z, x2, acc2[q4*4+2])));
            acc2[q4*4+3] = fmaf(a.w, x0, fmaf(bb.w, x1, fmaf(c.w, x2, acc2[q4*4+3])));
        }
    }
    __syncthreads();
    stage_ws(ws, Wt2 + 96*64, tid);      // W2 chunk1
    __syncthreads();
#pragma unroll 4
    for (int ii = 0; ii < 32; ++ii) {
        float x0 = t1[32+ii][2*p + 0], x1 = t1[32+ii][2*p + 1], x2 = t1[32+ii][2*p + 2];
        const float4* w0 = (const float4*)&ws[ii*3 + 0][oc];
        const float4* w1 = (const float4*)&ws[ii*3 + 1][oc];
        const float4* w2 = (const float4*)&ws[ii*3 + 2][oc];
#pragma unroll
        for (int q4 = 0; q4 < 2; ++q4) {
            float4 a = w0[q4], bb = w1[q4], c = w2[q4];
            acc2[q4*4+0] = fmaf(a.x, x0, fmaf(bb.x, x1, fmaf(c.x, x2, acc2[q4*4+0])));
            acc2[q4*4+1] = fmaf(a.y, x0, fmaf(bb.y, x1, fmaf(c.y, x2, acc2[q4*4+1])));
            acc2[q4*4+2] = fmaf(a.z, x0, fmaf(bb.z, x1, fmaf(c.z, x2, acc2[q4*4+2])));
            acc2[q4*4+3] = fmaf(a.w, x0, fmaf(bb.w, x1, fmaf(c.w, x2, acc2[q4*4+3])));
        }
    }

    bool valid = (p < 31) && (31*b + p < L3);
#pragma unroll
    for (int q = 0; q < 8; ++q) {
        float v = valid ? fmaxf(acc2[q], 0.f) : 0.f;
#pragma unroll
        for (int off = 1; off < 32; off <<= 1)
            v = fmaxf(v, __shfl_xor(v, off));
        if (p == 0) pmax[b * 64 + oc + q] = v;
    }
}

// ---------------------------------------------------------------------------
// Kernel 4: channel max over NBC block-partials, then the two FCs + sigmoid.
// ---------------------------------------------------------------------------
__global__ __launch_bounds__(64) void fc_k(const float* __restrict__ pmax,
                                           const float* __restrict__ Wf,
                                           const float* __restrict__ bf,
                                           const float* __restrict__ Wp,
                                           const float* __restrict__ bp,
                                           float* __restrict__ out)
{
    __shared__ float cm[64];
    __shared__ float ft[64];
    int t = threadIdx.x;
    float m = 0.f;
#pragma unroll
    for (int b = 0; b < NBC; ++b) m = fmaxf(m, pmax[b * 64 + t]);
    cm[t] = m;
    __syncthreads();
    float s = bf[t];
#pragma unroll
    for (int c = 0; c < 64; ++c) s = fmaf(Wf[t*64 + c], cm[c], s);
    float f = fmaxf(s, 0.f);
    ft[t] = f;
    out[t] = f;
    __syncthreads();
    if (t == 0) {
        float z = bp[0];
#pragma unroll
        for (int c = 0; c < 64; ++c) z = fmaf(Wp[c], ft[c], z);
        out[64] = 1.f / (1.f + expf(-z));
    }
}

// ---------------------------------------------------------------------------
extern "C" void kernel_launch(void* const* d_in, const int* in_sizes, int n_in,
                              void* d_out, int out_size, void* d_ws, size_t ws_size,
                              hipStream_t stream)
{
    const float* image   = (const float*)d_in[0];
    const float* corners = (const float*)d_in[1];
    const float* W0      = (const float*)d_in[2];
    const float* b0      = (const float*)d_in[3];
    const float* W1      = (const float*)d_in[4];
    const float* b1      = (const float*)d_in[5];
    const float* W2      = (const float*)d_in[6];
    const float* b2      = (const float*)d_in[7];
    const float* Wf      = (const float*)d_in[8];
    const float* bf      = (const float*)d_in[9];
    const float* Wp      = (const float*)d_in[10];
    const float* bp      = (const float*)d_in[11];
    float* out = (float*)d_out;

    // workspace layout (256B-aligned), ~21.8 MB used
    char* w = (char*)d_ws;
    unsigned* ctr     = (unsigned*)(w);              //      256 B
    double*   el2loc  = (double*)  (w + 256);        //   262144 B
    double*   partial = (double*)  (w + 262400);     //     1024 B
    float2*   pts     = (float2*)  (w + 263424);     //   262144 B
    int*      ridx    = (int*)     (w + 525568);     //   131072 B
    float*    pmax    = (float*)   (w + 656640);     //    34048 B
    float*    Wt      = (float*)   (w + 690688);     //   147456 B
    float*    imgT    = (float*)   (w + 838144);     // 16777216 B
    float*    Y0      = (float*)   (w + 17615360);   //  4210688 B -> 21826048

    hipMemsetAsync(ctr, 0, 256, stream);
    prep2_k  <<<PREP_GRID, 256, 0, stream>>>(corners, W0, W1, W2, image,
                                             el2loc, partial, pts, ridx, Wt, imgT, ctr);
    convA2_k <<<256, 256, 0, stream>>>(pts, ridx, imgT, Wt, b0, Y0);
    convBC_k <<<NBC, 256, 0, stream>>>(Y0, Wt + 12288, b1, Wt + 24576, b2, pmax);
    fc_k     <<<1, 64, 0, stream>>>(pmax, Wf, bf, Wp, bp, out);
}

// Round 10
// 61.608 us; speedup vs baseline: 1.6601x; 1.2150x over previous
//
#include <hip/hip_runtime.h>
#include <hip/hip_bf16.h>
#include <math.h>

// Problem constants (fixed by setup_inputs)
#define EDGES   32768
#define NPTS    32768
#define IMGH    256
#define L0      32768
#define L1      16384
#define L2      8192
#define L3      4096
#define S0      (L1 + 64)    // Y0 row stride (padded)
#define NBC     133          // convBC blocks (31 outputs each)

#define PB_SCAN 128
#define PB_T    1024
#define PREP_GRID (PB_SCAN + PB_T)    // 1152

// ---------------------------------------------------------------------------
// Self-staging weight transpose: original W[o][i][k] (o*192 + i*3 + k) ->
// ws[row][o], row = i*3+k in [chunk*96, chunk*96+96). 1536 float4 reads in
// ~384B contiguous runs (L2-resident), scalar LDS writes.
// ---------------------------------------------------------------------------
__device__ __forceinline__ void stage_wt(float ws[96][64],
                                         const float* __restrict__ W,
                                         int chunk, int tid)
{
    float4 v[6];
    int oo[6], mm[6];
#pragma unroll
    for (int j = 0; j < 6; ++j) {
        int f = j * 256 + tid;          // 0..1535
        int o = f / 24;
        int m = f - 24 * o;
        oo[j] = o; mm[j] = m;
        v[j] = *(const float4*)&W[o * 192 + chunk * 96 + m * 4];
    }
#pragma unroll
    for (int j = 0; j < 6; ++j) {
        ws[mm[j]*4 + 0][oo[j]] = v[j].x;
        ws[mm[j]*4 + 1][oo[j]] = v[j].y;
        ws[mm[j]*4 + 2][oo[j]] = v[j].z;
        ws[mm[j]*4 + 3][oo[j]] = v[j].w;
    }
}

// 64x64 k=3 stride-2 conv compute on a staged half.
__device__ __forceinline__ void conv_half(float acc[16],
                                          const float xs[64][130],
                                          const float ws[96][64],
                                          int ibase, int jl2, int o0)
{
#pragma unroll 4
    for (int ii = 0; ii < 32; ++ii) {
        int i = ibase + ii;
        float x0 = xs[i][jl2], x1 = xs[i][jl2 + 1], x2 = xs[i][jl2 + 2];
        const float4* w0 = (const float4*)&ws[ii*3 + 0][o0];
        const float4* w1 = (const float4*)&ws[ii*3 + 1][o0];
        const float4* w2 = (const float4*)&ws[ii*3 + 2][o0];
#pragma unroll
        for (int q = 0; q < 4; ++q) {
            float4 a = w0[q], b = w1[q], c = w2[q];
            acc[q*4+0] = fmaf(a.x, x0, fmaf(b.x, x1, fmaf(c.x, x2, acc[q*4+0])));
            acc[q*4+1] = fmaf(a.y, x0, fmaf(b.y, x1, fmaf(c.y, x2, acc[q*4+1])));
            acc[q*4+2] = fmaf(a.z, x0, fmaf(b.z, x1, fmaf(c.z, x2, acc[q*4+2])));
            acc[q*4+3] = fmaf(a.w, x0, fmaf(b.w, x1, fmaf(c.w, x2, acc[q*4+3])));
        }
    }
}

// ---------------------------------------------------------------------------
// Kernel 1 (prep3): scan (128 blocks) | vectorized image transpose (1024).
// No atomics, no spins.
// ---------------------------------------------------------------------------
__global__ __launch_bounds__(256) void prep3_k(const float* __restrict__ corners,
                                               const float* __restrict__ img,
                                               double* __restrict__ el2loc,
                                               double* __restrict__ partial,
                                               float*  __restrict__ imgT)
{
    __shared__ union {
        double sc[256];        // scan
        float  tt[64][68];     // transpose tile [pixel][channel]
    } sm;
    int b = blockIdx.x, t = threadIdx.x;

    if (b < PB_SCAN) {
        int e  = (b << 8) + t;
        int en = (e + 1) & (EDGES - 1);
        double dx = (double)corners[2*en]   - (double)corners[2*e];
        double dy = (double)corners[2*en+1] - (double)corners[2*e+1];
        sm.sc[t] = sqrt(dx*dx + dy*dy);
        __syncthreads();
        for (int o = 1; o < 256; o <<= 1) {        // Hillis-Steele inclusive
            double v = (t >= o) ? sm.sc[t - o] : 0.0;
            __syncthreads();
            sm.sc[t] += v;
            __syncthreads();
        }
        el2loc[e] = sm.sc[t];
        if (t == 255) partial[b] = sm.sc[255];
    } else {
        int tb   = b - PB_SCAN;
        int pix0 = tb << 6;                        // 64 pixels/block
        const float4* img4 = (const float4*)img;
#pragma unroll
        for (int k = 0; k < 4; ++k) {
            int idx = k*256 + t;
            if (idx < 992) {                       // 62 ch x 16 float4
                int c = idx >> 4, p4 = idx & 15;
                float4 v = img4[c*16384 + (pix0 >> 2) + p4];
                sm.tt[p4*4 + 0][c] = v.x;
                sm.tt[p4*4 + 1][c] = v.y;
                sm.tt[p4*4 + 2][c] = v.z;
                sm.tt[p4*4 + 3][c] = v.w;
            }
        }
        __syncthreads();
        float4* imgT4 = (float4*)imgT;
#pragma unroll
        for (int k = 0; k < 4; ++k) {
            int idx = k*256 + t;                   // < 1024
            int p = idx >> 4, c4 = idx & 15;
            if (c4 < 15) {
                float4 v = *(const float4*)&sm.tt[p][c4*4];
                imgT4[((size_t)(pix0 + p) << 4) + c4] = v;
            } else {                               // channels 60,61 (62/63 unused)
                float2 v = make_float2(sm.tt[p][60], sm.tt[p][61]);
                *(float2*)(imgT + ((size_t)(pix0 + p) << 6) + 60) = v;
            }
        }
    }
}

// ---------------------------------------------------------------------------
// Kernel 2 (convA3): per-block partial-scan + point search + gather + conv0.
// ---------------------------------------------------------------------------
__global__ __launch_bounds__(256) void convA3_k(const float* __restrict__ corners,
                                                const double* __restrict__ el2loc,
                                                const double* __restrict__ partial,
                                                const float* __restrict__ imgT,
                                                const float* __restrict__ W0,
                                                const float* __restrict__ b0v,
                                                float* __restrict__ Y0)
{
    __shared__ float  xs[64][130];   // 33280 B
    __shared__ float  ws[96][64];    // 24576 B
    __shared__ double sb[128];       //  1024 B
    int tid = threadIdx.x;
    int b   = blockIdx.x;
    int j0  = b << 6;
    int in0 = (j0 << 1) - 1;

    // in-block inclusive scan of the 128 chunk partials
    if (tid < 128) sb[tid] = partial[tid];
    __syncthreads();
#pragma unroll
    for (int o = 1; o < 128; o <<= 1) {
        double v = 0.0;
        if (tid < 128 && tid >= o) v = sb[tid - o];
        __syncthreads();
        if (tid < 128) sb[tid] += v;
        __syncthreads();
    }

    stage_wt(ws, W0, 0, tid);                      // W0 chunk 0 (all threads)

    if (tid < 130) {
        int g = in0 + tid;
        if (g < 0)   g = 1;                        // reflect left
        if (g >= L0) g = 2*L0 - 2 - g;             // halo guard
        double S   = sb[127];
        double off = (double)g * (S * (1.0 / (double)NPTS));
        // two-level lower_bound: 7 LDS levels + 8 global levels
        int clo = 0, chi = 127;
        while (clo < chi) { int cm = (clo + chi) >> 1;
                            if (sb[cm] > off) chi = cm; else clo = cm + 1; }
        double base = clo ? sb[clo - 1] : 0.0;
        int lo = clo << 8, hi = lo + 255;
        while (lo < hi) { int mid = (lo + hi) >> 1;
                          if (el2loc[mid] + base > off) hi = mid; else lo = mid + 1; }
        int e = lo;
        double e1 = (e == 0) ? 0.0
                  : el2loc[e-1] + (((e-1) >= 256) ? sb[((e-1) >> 8) - 1] : 0.0);
        float sxf = corners[2*e], syf = corners[2*e+1];
        int en = (e + 1) & (EDGES - 1);
        double dx = (double)corners[2*en]   - (double)sxf;
        double dy = (double)corners[2*en+1] - (double)syf;
        double len = sqrt(dx*dx + dy*dy);
        double tp  = (off - e1) / fmax(len, 0.0001);
        double px  = (double)sxf + tp * dx;
        double py  = (double)syf + tp * dy;
        int r0 = (int)rint(px * (double)IMGH); r0 = r0 < 0 ? 0 : (r0 > IMGH-1 ? IMGH-1 : r0);
        int r1 = (int)rint(py * (double)IMGH); r1 = r1 < 0 ? 0 : (r1 > IMGH-1 ? IMGH-1 : r1);
        const float4* row4 = (const float4*)(imgT + ((size_t)((r0 << 8) | r1) << 6));
        float4 rv[15];
#pragma unroll
        for (int c4 = 0; c4 < 15; ++c4) rv[c4] = row4[c4];
        float c60 = ((const float*)row4)[60], c61 = ((const float*)row4)[61];
#pragma unroll
        for (int c4 = 0; c4 < 15; ++c4) {
            xs[c4*4 + 0][tid] = rv[c4].x;
            xs[c4*4 + 1][tid] = rv[c4].y;
            xs[c4*4 + 2][tid] = rv[c4].z;
            xs[c4*4 + 3][tid] = rv[c4].w;
        }
        xs[60][tid] = c60;
        xs[61][tid] = c61;
        xs[62][tid] = (float)px;
        xs[63][tid] = (float)py;
    }
    __syncthreads();

    int lane = tid & 63;
    int o0   = (tid >> 6) << 4;
    float acc[16];
#pragma unroll
    for (int m = 0; m < 16; ++m) acc[m] = b0v[o0 + m];
    int jl2 = lane << 1;

    conv_half(acc, xs, ws, 0, jl2, o0);
    __syncthreads();
    stage_wt(ws, W0, 1, tid);                      // W0 chunk 1
    __syncthreads();
    conv_half(acc, xs, ws, 32, jl2, o0);

    int j = j0 + lane;
#pragma unroll
    for (int m = 0; m < 16; ++m)
        Y0[(o0 + m) * S0 + j] = fmaxf(acc[m], 0.f);
}

// ---------------------------------------------------------------------------
// Kernel 3 (convBC2): conv1 + conv2 fused; Y1 never materialized.
// ---------------------------------------------------------------------------
__global__ __launch_bounds__(256) void convBC2_k(const float* __restrict__ Y0,
                                                 const float* __restrict__ W1,
                                                 const float* __restrict__ b1,
                                                 const float* __restrict__ W2,
                                                 const float* __restrict__ b2,
                                                 float* __restrict__ pmax)
{
    __shared__ float xs0[32][132];   // 16896 B
    __shared__ float t1[64][63];     // 16128 B
    __shared__ float ws[96][64];     // 24576 B
    int tid = threadIdx.x;
    int b   = blockIdx.x;
    int gbase = 124*b - 3;

    int s  = tid & 63;
    int o0 = (tid >> 6) << 4;
    int j1 = 62*b - 1 + s;
    int jr = (j1 < 0) ? -j1 : (j1 > L2-1 ? L2-1 : j1);   // reflect/clamp (halo-safe)
    int col0 = 2*jr - 124*b + 2;

    {   // stage Y0 half-0 (in-ch 0..31) + W1 chunk0
        float r[16];
#pragma unroll
        for (int k = 0; k < 16; ++k) {
            int idx = k*256 + tid;
            int c   = idx >> 7, col = idx & 127;
            int g   = gbase + col;
            if (g < 0)   g = -g;
            if (g >= L1) g = 2*L1 - 2 - g;
            r[k] = Y0[c * S0 + g];
        }
        stage_wt(ws, W1, 0, tid);
#pragma unroll
        for (int k = 0; k < 16; ++k) {
            int idx = k*256 + tid;
            xs0[idx >> 7][idx & 127] = r[k];
        }
    }
    __syncthreads();

    float acc1[16];
#pragma unroll
    for (int m = 0; m < 16; ++m) acc1[m] = b1[o0 + m];
#pragma unroll 4
    for (int ii = 0; ii < 32; ++ii) {
        float x0 = xs0[ii][col0], x1 = xs0[ii][col0+1], x2 = xs0[ii][col0+2];
        const float4* w0 = (const float4*)&ws[ii*3 + 0][o0];
        const float4* w1 = (const float4*)&ws[ii*3 + 1][o0];
        const float4* w2 = (const float4*)&ws[ii*3 + 2][o0];
#pragma unroll
        for (int q = 0; q < 4; ++q) {
            float4 a = w0[q], bb = w1[q], c = w2[q];
            acc1[q*4+0] = fmaf(a.x, x0, fmaf(bb.x, x1, fmaf(c.x, x2, acc1[q*4+0])));
            acc1[q*4+1] = fmaf(a.y, x0, fmaf(bb.y, x1, fmaf(c.y, x2, acc1[q*4+1])));
            acc1[q*4+2] = fmaf(a.z, x0, fmaf(bb.z, x1, fmaf(c.z, x2, acc1[q*4+2])));
            acc1[q*4+3] = fmaf(a.w, x0, fmaf(bb.w, x1, fmaf(c.w, x2, acc1[q*4+3])));
        }
    }
    __syncthreads();
    {   // stage Y0 half-1 (in-ch 32..63) + W1 chunk1
        float r[16];
#pragma unroll
        for (int k = 0; k < 16; ++k) {
            int idx = k*256 + tid;
            int c   = idx >> 7, col = idx & 127;
            int g   = gbase + col;
            if (g < 0)   g = -g;
            if (g >= L1) g = 2*L1 - 2 - g;
            r[k] = Y0[(32 + c) * S0 + g];
        }
        stage_wt(ws, W1, 1, tid);
#pragma unroll
        for (int k = 0; k < 16; ++k) {
            int idx = k*256 + tid;
            xs0[idx >> 7][idx & 127] = r[k];
        }
    }
    __syncthreads();
#pragma unroll 4
    for (int ii = 0; ii < 32; ++ii) {
        float x0 = xs0[ii][col0], x1 = xs0[ii][col0+1], x2 = xs0[ii][col0+2];
        const float4* w0 = (const float4*)&ws[ii*3 + 0][o0];
        const float4* w1 = (const float4*)&ws[ii*3 + 1][o0];
        const float4* w2 = (const float4*)&ws[ii*3 + 2][o0];
#pragma unroll
        for (int q = 0; q < 4; ++q) {
            float4 a = w0[q], bb = w1[q], c = w2[q];
            acc1[q*4+0] = fmaf(a.x, x0, fmaf(bb.x, x1, fmaf(c.x, x2, acc1[q*4+0])));
            acc1[q*4+1] = fmaf(a.y, x0, fmaf(bb.y, x1, fmaf(c.y, x2, acc1[q*4+1])));
            acc1[q*4+2] = fmaf(a.z, x0, fmaf(bb.z, x1, fmaf(c.z, x2, acc1[q*4+2])));
            acc1[q*4+3] = fmaf(a.w, x0, fmaf(bb.w, x1, fmaf(c.w, x2, acc1[q*4+3])));
        }
    }
    __syncthreads();
    if (s < 63) {
#pragma unroll
        for (int m = 0; m < 16; ++m) t1[o0 + m][s] = fmaxf(acc1[m], 0.f);
    }
    __syncthreads();

    // conv2: thread -> (pos p, 8-ch group)
    int p  = tid & 31;
    int oc = (tid >> 5) << 3;
    float acc2[8];
#pragma unroll
    for (int q = 0; q < 8; ++q) acc2[q] = b2[oc + q];

    stage_wt(ws, W2, 0, tid);            // W2 chunk0
    __syncthreads();
#pragma unroll 4
    for (int ii = 0; ii < 32; ++ii) {
        float x0 = t1[ii][2*p + 0], x1 = t1[ii][2*p + 1], x2 = t1[ii][2*p + 2];
        const float4* w0 = (const float4*)&ws[ii*3 + 0][oc];
        const float4* w1 = (const float4*)&ws[ii*3 + 1][oc];
        const float4* w2 = (const float4*)&ws[ii*3 + 2][oc];
#pragma unroll
        for (int q4 = 0; q4 < 2; ++q4) {
            float4 a = w0[q4], bb = w1[q4], c = w2[q4];
            acc2[q4*4+0] = fmaf(a.x, x0, fmaf(bb.x, x1, fmaf(c.x, x2, acc2[q4*4+0])));
            acc2[q4*4+1] = fmaf(a.y, x0, fmaf(bb.y, x1, fmaf(c.y, x2, acc2[q4*4+1])));
            acc2[q4*4+2] = fmaf(a.z, x0, fmaf(bb.z, x1, fmaf(c.z, x2, acc2[q4*4+2])));
            acc2[q4*4+3] = fmaf(a.w, x0, fmaf(bb.w, x1, fmaf(c.w, x2, acc2[q4*4+3])));
        }
    }
    __syncthreads();
    stage_wt(ws, W2, 1, tid);            // W2 chunk1
    __syncthreads();
#pragma unroll 4
    for (int ii = 0; ii < 32; ++ii) {
        float x0 = t1[32+ii][2*p + 0], x1 = t1[32+ii][2*p + 1], x2 = t1[32+ii][2*p + 2];
        const float4* w0 = (const float4*)&ws[ii*3 + 0][oc];
        const float4* w1 = (const float4*)&ws[ii*3 + 1][oc];
        const float4* w2 = (const float4*)&ws[ii*3 + 2][oc];
#pragma unroll
        for (int q4 = 0; q4 < 2; ++q4) {
            float4 a = w0[q4], bb = w1[q4], c = w2[q4];
            acc2[q4*4+0] = fmaf(a.x, x0, fmaf(bb.x, x1, fmaf(c.x, x2, acc2[q4*4+0])));
            acc2[q4*4+1] = fmaf(a.y, x0, fmaf(bb.y, x1, fmaf(c.y, x2, acc2[q4*4+1])));
            acc2[q4*4+2] = fmaf(a.z, x0, fmaf(bb.z, x1, fmaf(c.z, x2, acc2[q4*4+2])));
            acc2[q4*4+3] = fmaf(a.w, x0, fmaf(bb.w, x1, fmaf(c.w, x2, acc2[q4*4+3])));
        }
    }

    bool valid = (p < 31) && (31*b + p < L3);
#pragma unroll
    for (int q = 0; q < 8; ++q) {
        float v = valid ? fmaxf(acc2[q], 0.f) : 0.f;
#pragma unroll
        for (int off = 1; off < 32; off <<= 1)
            v = fmaxf(v, __shfl_xor(v, off));
        if (p == 0) pmax[b * 64 + oc + q] = v;
    }
}

// ---------------------------------------------------------------------------
// Kernel 4: channel max over NBC block-partials, then the two FCs + sigmoid.
// ---------------------------------------------------------------------------
__global__ __launch_bounds__(64) void fc_k(const float* __restrict__ pmax,
                                           const float* __restrict__ Wf,
                                           const float* __restrict__ bf,
                                           const float* __restrict__ Wp,
                                           const float* __restrict__ bp,
                                           float* __restrict__ out)
{
    __shared__ float cm[64];
    __shared__ float ft[64];
    int t = threadIdx.x;
    float m = 0.f;
#pragma unroll
    for (int b = 0; b < NBC; ++b) m = fmaxf(m, pmax[b * 64 + t]);
    cm[t] = m;
    __syncthreads();
    float s = bf[t];
#pragma unroll
    for (int c = 0; c < 64; ++c) s = fmaf(Wf[t*64 + c], cm[c], s);
    float f = fmaxf(s, 0.f);
    ft[t] = f;
    out[t] = f;
    __syncthreads();
    if (t == 0) {
        float z = bp[0];
#pragma unroll
        for (int c = 0; c < 64; ++c) z = fmaf(Wp[c], ft[c], z);
        out[64] = 1.f / (1.f + expf(-z));
    }
}

// ---------------------------------------------------------------------------
extern "C" void kernel_launch(void* const* d_in, const int* in_sizes, int n_in,
                              void* d_out, int out_size, void* d_ws, size_t ws_size,
                              hipStream_t stream)
{
    const float* image   = (const float*)d_in[0];
    const float* corners = (const float*)d_in[1];
    const float* W0      = (const float*)d_in[2];
    const float* b0      = (const float*)d_in[3];
    const float* W1      = (const float*)d_in[4];
    const float* b1      = (const float*)d_in[5];
    const float* W2      = (const float*)d_in[6];
    const float* b2      = (const float*)d_in[7];
    const float* Wf      = (const float*)d_in[8];
    const float* bf      = (const float*)d_in[9];
    const float* Wp      = (const float*)d_in[10];
    const float* bp      = (const float*)d_in[11];
    float* out = (float*)d_out;

    // workspace layout (256B-aligned), ~21.3 MB used
    char* w = (char*)d_ws;
    double* el2loc  = (double*)(w);                  //   262144 B
    double* partial = (double*)(w + 262144);         //     1024 B
    float*  pmax    = (float*) (w + 263168);         //    34048 B
    float*  imgT    = (float*) (w + 297216);         // 16777216 B
    float*  Y0      = (float*) (w + 17074432);       //  4210688 B -> 21285120

    prep3_k  <<<PREP_GRID, 256, 0, stream>>>(corners, image, el2loc, partial, imgT);
    convA3_k <<<256, 256, 0, stream>>>(corners, el2loc, partial, imgT, W0, b0, Y0);
    convBC2_k<<<NBC, 256, 0, stream>>>(Y0, W1, b1, W2, b2, pmax);
    fc_k     <<<1, 64, 0, stream>>>(pmax, Wf, bf, Wp, bp, out);
}

// Round 11
// 56.298 us; speedup vs baseline: 1.8166x; 1.0943x over previous
//
#include <hip/hip_runtime.h>
#include <hip/hip_bf16.h>
#include <math.h>

// Problem constants (fixed by setup_inputs)
#define EDGES   32768
#define NPTS    32768
#define IMGH    256
#define L0      32768
#define L1      16384
#define L2      8192
#define L3      4096
#define S0      (L1 + 64)    // Y0 row stride (padded)
#define NBC     133          // convBC blocks (31 outputs each)

// prep_rest block ranges: [0,128) gather | [128,146) weights | [146,1170) transpose
#define PR_GATHER 128
#define PR_W      18
#define PR_T      1024
#define PREST_GRID (PR_GATHER + PR_W + PR_T)   // 1170

// Batched weight-chunk staging from pre-transposed Wt: 1536 float4, 6/thread.
__device__ __forceinline__ void stage_ws(float ws[96][64],
                                         const float* __restrict__ Wsrc, int tid)
{
    const float4* src = (const float4*)Wsrc;
    float4 rw[6];
#pragma unroll
    for (int k = 0; k < 6; ++k) rw[k] = src[k * 256 + tid];
    float4* dst = (float4*)&ws[0][0];
#pragma unroll
    for (int k = 0; k < 6; ++k) dst[k * 256 + tid] = rw[k];
}

// 64x64 k=3 stride-2 conv compute on a staged half.
__device__ __forceinline__ void conv_half(float acc[16],
                                          const float xs[64][130],
                                          const float ws[96][64],
                                          int ibase, int jl2, int o0)
{
#pragma unroll 4
    for (int ii = 0; ii < 32; ++ii) {
        int i = ibase + ii;
        float x0 = xs[i][jl2], x1 = xs[i][jl2 + 1], x2 = xs[i][jl2 + 2];
        const float4* w0 = (const float4*)&ws[ii*3 + 0][o0];
        const float4* w1 = (const float4*)&ws[ii*3 + 1][o0];
        const float4* w2 = (const float4*)&ws[ii*3 + 2][o0];
#pragma unroll
        for (int q = 0; q < 4; ++q) {
            float4 a = w0[q], b = w1[q], c = w2[q];
            acc[q*4+0] = fmaf(a.x, x0, fmaf(b.x, x1, fmaf(c.x, x2, acc[q*4+0])));
            acc[q*4+1] = fmaf(a.y, x0, fmaf(b.y, x1, fmaf(c.y, x2, acc[q*4+1])));
            acc[q*4+2] = fmaf(a.z, x0, fmaf(b.z, x1, fmaf(c.z, x2, acc[q*4+2])));
            acc[q*4+3] = fmaf(a.w, x0, fmaf(b.w, x1, fmaf(c.w, x2, acc[q*4+3])));
        }
    }
}

// ---------------------------------------------------------------------------
// Kernel 1 (prep_scan): 128 blocks x 256: edge lengths (f64) + in-block
// inclusive scan -> el2loc (local cumsum), partial[block].
// ---------------------------------------------------------------------------
__global__ __launch_bounds__(256) void prep_scan_k(const float* __restrict__ corners,
                                                   double* __restrict__ el2loc,
                                                   double* __restrict__ partial)
{
    __shared__ double sc[256];
    int b = blockIdx.x, t = threadIdx.x;
    int e  = (b << 8) + t;
    int en = (e + 1) & (EDGES - 1);
    double dx = (double)corners[2*en]   - (double)corners[2*e];
    double dy = (double)corners[2*en+1] - (double)corners[2*e+1];
    sc[t] = sqrt(dx*dx + dy*dy);
    __syncthreads();
    for (int o = 1; o < 256; o <<= 1) {        // Hillis-Steele inclusive
        double v = (t >= o) ? sc[t - o] : 0.0;
        __syncthreads();
        sc[t] += v;
        __syncthreads();
    }
    el2loc[e] = sc[t];
    if (t == 255) partial[b] = sc[255];
}

// ---------------------------------------------------------------------------
// Kernel 2 (prep_rest): gather | weight transpose | image transpose.
// Kernel boundary after prep_scan provides the sync (no atomics/spins).
// ---------------------------------------------------------------------------
__global__ __launch_bounds__(256) void prep_rest_k(const float* __restrict__ corners,
                                                   const float* __restrict__ W0,
                                                   const float* __restrict__ W1,
                                                   const float* __restrict__ W2,
                                                   const float* __restrict__ img,
                                                   const double* __restrict__ el2loc,
                                                   const double* __restrict__ partial,
                                                   float2* __restrict__ pts,
                                                   int*    __restrict__ ridx,
                                                   float*  __restrict__ Wt,
                                                   float*  __restrict__ imgT)
{
    __shared__ union {
        double sb[128];        // gather chunk offsets
        float  tt[64][68];     // transpose tile [pixel][channel]
    } sm;
    int b = blockIdx.x, t = threadIdx.x;

    if (b < PR_GATHER) {
        // ---- per-point arc-length placement -> pts, ridx ----
        if (t < 128) sm.sb[t] = partial[t];
        __syncthreads();
        for (int o = 1; o < 128; o <<= 1) {
            double v = 0.0;
            if (t < 128 && t >= o) v = sm.sb[t - o];
            __syncthreads();
            if (t < 128) sm.sb[t] += v;
            __syncthreads();
        }
        int p = (b << 8) + t;
        double S   = sm.sb[127];
        double off = (double)p * (S * (1.0 / (double)NPTS));
        int clo = 0, chi = 127;
        while (clo < chi) { int cm = (clo + chi) >> 1;
                            if (sm.sb[cm] > off) chi = cm; else clo = cm + 1; }
        double base = clo ? sm.sb[clo - 1] : 0.0;
        int lo = clo << 8, hi = lo + 255;
        while (lo < hi) { int mid = (lo + hi) >> 1;
                          if (el2loc[mid] + base > off) hi = mid; else lo = mid + 1; }
        int e = lo;
        double e1 = (e == 0) ? 0.0
                  : el2loc[e-1] + (((e-1) >= 256) ? sm.sb[((e-1) >> 8) - 1] : 0.0);
        float sxf = corners[2*e], syf = corners[2*e+1];
        int en = (e + 1) & (EDGES - 1);
        double dx = (double)corners[2*en]   - (double)sxf;
        double dy = (double)corners[2*en+1] - (double)syf;
        double len = sqrt(dx*dx + dy*dy);
        double tp  = (off - e1) / fmax(len, 0.0001);
        double px  = (double)sxf + tp * dx;
        double py  = (double)syf + tp * dy;
        int r0 = (int)rint(px * (double)IMGH); r0 = r0 < 0 ? 0 : (r0 > IMGH-1 ? IMGH-1 : r0);
        int r1 = (int)rint(py * (double)IMGH); r1 = r1 < 0 ? 0 : (r1 > IMGH-1 ? IMGH-1 : r1);
        pts[p]  = make_float2((float)px, (float)py);
        ridx[p] = (r0 << 8) | r1;
    } else if (b < PR_GATHER + PR_W) {
        // ---- weight transpose W[o][i][k] -> Wt[(i*3+k)*64+o], 3 layers ----
        int wb = b - PR_GATHER;
#pragma unroll
        for (int k = 0; k < 8; ++k) {
            int idx = wb*2048 + k*256 + t;         // < 36864 exactly
            int l   = idx / 12288;
            int rem = idx - l * 12288;
            int row = rem >> 6, o = rem & 63;
            int i   = row / 3,  kk = row - i * 3;
            const float* W = (l == 0) ? W0 : ((l == 1) ? W1 : W2);
            Wt[idx] = W[o*192 + i*3 + kk];
        }
    } else {
        // ---- vectorized image transpose (62,256,256) -> (65536,64) ----
        int tb   = b - (PR_GATHER + PR_W);
        int pix0 = tb << 6;                        // 64 pixels/block
        const float4* img4 = (const float4*)img;
#pragma unroll
        for (int k = 0; k < 4; ++k) {
            int idx = k*256 + t;
            if (idx < 992) {                       // 62 ch x 16 float4
                int c = idx >> 4, p4 = idx & 15;
                float4 v = img4[c*16384 + (pix0 >> 2) + p4];
                sm.tt[p4*4 + 0][c] = v.x;
                sm.tt[p4*4 + 1][c] = v.y;
                sm.tt[p4*4 + 2][c] = v.z;
                sm.tt[p4*4 + 3][c] = v.w;
            }
        }
        __syncthreads();
        float4* imgT4 = (float4*)imgT;
#pragma unroll
        for (int k = 0; k < 4; ++k) {
            int idx = k*256 + t;                   // < 1024
            int p = idx >> 4, c4 = idx & 15;
            if (c4 < 15) {
                float4 v = *(const float4*)&sm.tt[p][c4*4];
                imgT4[((size_t)(pix0 + p) << 4) + c4] = v;
            } else {                               // channels 60,61 (62/63 unused)
                float2 v = make_float2(sm.tt[p][60], sm.tt[p][61]);
                *(float2*)(imgT + ((size_t)(pix0 + p) << 6) + 60) = v;
            }
        }
    }
}

// ---------------------------------------------------------------------------
// Kernel 3 (convA2): gather (precomputed pts/ridx) + conv layer 0 -> Y0.
// ---------------------------------------------------------------------------
__global__ __launch_bounds__(256) void convA2_k(const float2* __restrict__ pts,
                                                const int*    __restrict__ ridx,
                                                const float*  __restrict__ imgT,
                                                const float*  __restrict__ Wt,
                                                const float*  __restrict__ b0v,
                                                float* __restrict__ Y0)
{
    __shared__ float xs[64][130];   // 33280 B
    __shared__ float ws[96][64];    // 24576 B
    int tid = threadIdx.x;
    int b   = blockIdx.x;
    int j0  = b << 6;
    int in0 = (j0 << 1) - 1;

    stage_ws(ws, Wt, tid);                         // W0 chunk 0
    if (tid < 130) {
        int g = in0 + tid;
        if (g < 0)   g = 1;                        // reflect left
        if (g >= L0) g = 2*L0 - 2 - g;             // halo guard
        float2 pxy = pts[g];
        int    rid = ridx[g];
        const float4* row4 = (const float4*)(imgT + ((size_t)rid << 6));
        float4 rv[15];
#pragma unroll
        for (int c4 = 0; c4 < 15; ++c4) rv[c4] = row4[c4];
        float c60 = ((const float*)row4)[60], c61 = ((const float*)row4)[61];
#pragma unroll
        for (int c4 = 0; c4 < 15; ++c4) {
            xs[c4*4 + 0][tid] = rv[c4].x;
            xs[c4*4 + 1][tid] = rv[c4].y;
            xs[c4*4 + 2][tid] = rv[c4].z;
            xs[c4*4 + 3][tid] = rv[c4].w;
        }
        xs[60][tid] = c60;
        xs[61][tid] = c61;
        xs[62][tid] = pxy.x;
        xs[63][tid] = pxy.y;
    }
    __syncthreads();

    int lane = tid & 63;
    int o0   = (tid >> 6) << 4;
    float acc[16];
#pragma unroll
    for (int m = 0; m < 16; ++m) acc[m] = b0v[o0 + m];
    int jl2 = lane << 1;

    conv_half(acc, xs, ws, 0, jl2, o0);
    __syncthreads();
    stage_ws(ws, Wt + 96*64, tid);                 // W0 chunk 1
    __syncthreads();
    conv_half(acc, xs, ws, 32, jl2, o0);

    int j = j0 + lane;
#pragma unroll
    for (int m = 0; m < 16; ++m)
        Y0[(o0 + m) * S0 + j] = fmaxf(acc[m], 0.f);
}

// ---------------------------------------------------------------------------
// Kernel 4 (convBC): conv1 + conv2 fused; Y1 never materialized.
// ---------------------------------------------------------------------------
__global__ __launch_bounds__(256) void convBC_k(const float* __restrict__ Y0,
                                                const float* __restrict__ Wt1,
                                                const float* __restrict__ b1,
                                                const float* __restrict__ Wt2,
                                                const float* __restrict__ b2,
                                                float* __restrict__ pmax)
{
    __shared__ float xs0[32][132];   // 16896 B
    __shared__ float t1[64][63];     // 16128 B
    __shared__ float ws[96][64];     // 24576 B
    int tid = threadIdx.x;
    int b   = blockIdx.x;
    int gbase = 124*b - 3;

    int s  = tid & 63;
    int o0 = (tid >> 6) << 4;
    int j1 = 62*b - 1 + s;
    int jr = (j1 < 0) ? -j1 : (j1 > L2-1 ? L2-1 : j1);
    int col0 = 2*jr - 124*b + 2;

    {   // stage Y0 half-0 (in-ch 0..31) + W1 chunk0
        float r[16];
#pragma unroll
        for (int k = 0; k < 16; ++k) {
            int idx = k*256 + tid;
            int c   = idx >> 7, col = idx & 127;
            int g   = gbase + col;
            if (g < 0)   g = -g;
            if (g >= L1) g = 2*L1 - 2 - g;
            r[k] = Y0[c * S0 + g];
        }
        stage_ws(ws, Wt1, tid);
#pragma unroll
        for (int k = 0; k < 16; ++k) {
            int idx = k*256 + tid;
            xs0[idx >> 7][idx & 127] = r[k];
        }
    }
    __syncthreads();

    float acc1[16];
#pragma unroll
    for (int m = 0; m < 16; ++m) acc1[m] = b1[o0 + m];
#pragma unroll 4
    for (int ii = 0; ii < 32; ++ii) {
        float x0 = xs0[ii][col0], x1 = xs0[ii][col0+1], x2 = xs0[ii][col0+2];
        const float4* w0 = (const float4*)&ws[ii*3 + 0][o0];
        const float4* w1 = (const float4*)&ws[ii*3 + 1][o0];
        const float4* w2 = (const float4*)&ws[ii*3 + 2][o0];
#pragma unroll
        for (int q = 0; q < 4; ++q) {
            float4 a = w0[q], bb = w1[q], c = w2[q];
            acc1[q*4+0] = fmaf(a.x, x0, fmaf(bb.x, x1, fmaf(c.x, x2, acc1[q*4+0])));
            acc1[q*4+1] = fmaf(a.y, x0, fmaf(bb.y, x1, fmaf(c.y, x2, acc1[q*4+1])));
            acc1[q*4+2] = fmaf(a.z, x0, fmaf(bb.z, x1, fmaf(c.z, x2, acc1[q*4+2])));
            acc1[q*4+3] = fmaf(a.w, x0, fmaf(bb.w, x1, fmaf(c.w, x2, acc1[q*4+3])));
        }
    }
    __syncthreads();
    {   // stage Y0 half-1 (in-ch 32..63) + W1 chunk1
        float r[16];
#pragma unroll
        for (int k = 0; k < 16; ++k) {
            int idx = k*256 + tid;
            int c   = idx >> 7, col = idx & 127;
            int g   = gbase + col;
            if (g < 0)   g = -g;
            if (g >= L1) g = 2*L1 - 2 - g;
            r[k] = Y0[(32 + c) * S0 + g];
        }
        stage_ws(ws, Wt1 + 96*64, tid);
#pragma unroll
        for (int k = 0; k < 16; ++k) {
            int idx = k*256 + tid;
            xs0[idx >> 7][idx & 127] = r[k];
        }
    }
    __syncthreads();
#pragma unroll 4
    for (int ii = 0; ii < 32; ++ii) {
        float x0 = xs0[ii][col0], x1 = xs0[ii][col0+1], x2 = xs0[ii][col0+2];
        const float4* w0 = (const float4*)&ws[ii*3 + 0][o0];
        const float4* w1 = (const float4*)&ws[ii*3 + 1][o0];
        const float4* w2 = (const float4*)&ws[ii*3 + 2][o0];
#pragma unroll
        for (int q = 0; q < 4; ++q) {
            float4 a = w0[q], bb = w1[q], c = w2[q];
            acc1[q*4+0] = fmaf(a.x, x0, fmaf(bb.x, x1, fmaf(c.x, x2, acc1[q*4+0])));
            acc1[q*4+1] = fmaf(a.y, x0, fmaf(bb.y, x1, fmaf(c.y, x2, acc1[q*4+1])));
            acc1[q*4+2] = fmaf(a.z, x0, fmaf(bb.z, x1, fmaf(c.z, x2, acc1[q*4+2])));
            acc1[q*4+3] = fmaf(a.w, x0, fmaf(bb.w, x1, fmaf(c.w, x2, acc1[q*4+3])));
        }
    }
    __syncthreads();
    if (s < 63) {
#pragma unroll
        for (int m = 0; m < 16; ++m) t1[o0 + m][s] = fmaxf(acc1[m], 0.f);
    }
    __syncthreads();

    // conv2: thread -> (pos p, 8-ch group)
    int p  = tid & 31;
    int oc = (tid >> 5) << 3;
    float acc2[8];
#pragma unroll
    for (int q = 0; q < 8; ++q) acc2[q] = b2[oc + q];

    stage_ws(ws, Wt2, tid);              // W2 chunk0
    __syncthreads();
#pragma unroll 4
    for (int ii = 0; ii < 32; ++ii) {
        float x0 = t1[ii][2*p + 0], x1 = t1[ii][2*p + 1], x2 = t1[ii][2*p + 2];
        const float4* w0 = (const float4*)&ws[ii*3 + 0][oc];
        const float4* w1 = (const float4*)&ws[ii*3 + 1][oc];
        const float4* w2 = (const float4*)&ws[ii*3 + 2][oc];
#pragma unroll
        for (int q4 = 0; q4 < 2; ++q4) {
            float4 a = w0[q4], bb = w1[q4], c = w2[q4];
            acc2[q4*4+0] = fmaf(a.x, x0, fmaf(bb.x, x1, fmaf(c.x, x2, acc2[q4*4+0])));
            acc2[q4*4+1] = fmaf(a.y, x0, fmaf(bb.y, x1, fmaf(c.y, x2, acc2[q4*4+1])));
            acc2[q4*4+2] = fmaf(a.z, x0, fmaf(bb.z, x1, fmaf(c.z, x2, acc2[q4*4+2])));
            acc2[q4*4+3] = fmaf(a.w, x0, fmaf(bb.w, x1, fmaf(c.w, x2, acc2[q4*4+3])));
        }
    }
    __syncthreads();
    stage_ws(ws, Wt2 + 96*64, tid);      // W2 chunk1
    __syncthreads();
#pragma unroll 4
    for (int ii = 0; ii < 32; ++ii) {
        float x0 = t1[32+ii][2*p + 0], x1 = t1[32+ii][2*p + 1], x2 = t1[32+ii][2*p + 2];
        const float4* w0 = (const float4*)&ws[ii*3 + 0][oc];
        const float4* w1 = (const float4*)&ws[ii*3 + 1][oc];
        const float4* w2 = (const float4*)&ws[ii*3 + 2][oc];
#pragma unroll
        for (int q4 = 0; q4 < 2; ++q4) {
            float4 a = w0[q4], bb = w1[q4], c = w2[q4];
            acc2[q4*4+0] = fmaf(a.x, x0, fmaf(bb.x, x1, fmaf(c.x, x2, acc2[q4*4+0])));
            acc2[q4*4+1] = fmaf(a.y, x0, fmaf(bb.y, x1, fmaf(c.y, x2, acc2[q4*4+1])));
            acc2[q4*4+2] = fmaf(a.z, x0, fmaf(bb.z, x1, fmaf(c.z, x2, acc2[q4*4+2])));
            acc2[q4*4+3] = fmaf(a.w, x0, fmaf(bb.w, x1, fmaf(c.w, x2, acc2[q4*4+3])));
        }
    }

    bool valid = (p < 31) && (31*b + p < L3);
#pragma unroll
    for (int q = 0; q < 8; ++q) {
        float v = valid ? fmaxf(acc2[q], 0.f) : 0.f;
#pragma unroll
        for (int off = 1; off < 32; off <<= 1)
            v = fmaxf(v, __shfl_xor(v, off));
        if (p == 0) pmax[b * 64 + oc + q] = v;
    }
}

// ---------------------------------------------------------------------------
// Kernel 5: channel max over NBC block-partials, then the two FCs + sigmoid.
// ---------------------------------------------------------------------------
__global__ __launch_bounds__(64) void fc_k(const float* __restrict__ pmax,
                                           const float* __restrict__ Wf,
                                           const float* __restrict__ bf,
                                           const float* __restrict__ Wp,
                                           const float* __restrict__ bp,
                                           float* __restrict__ out)
{
    __shared__ float cm[64];
    __shared__ float ft[64];
    int t = threadIdx.x;
    float m = 0.f;
#pragma unroll
    for (int b = 0; b < NBC; ++b) m = fmaxf(m, pmax[b * 64 + t]);
    cm[t] = m;
    __syncthreads();
    float s = bf[t];
#pragma unroll
    for (int c = 0; c < 64; ++c) s = fmaf(Wf[t*64 + c], cm[c], s);
    float f = fmaxf(s, 0.f);
    ft[t] = f;
    out[t] = f;
    __syncthreads();
    if (t == 0) {
        float z = bp[0];
#pragma unroll
        for (int c = 0; c < 64; ++c) z = fmaf(Wp[c], ft[c], z);
        out[64] = 1.f / (1.f + expf(-z));
    }
}

// ---------------------------------------------------------------------------
extern "C" void kernel_launch(void* const* d_in, const int* in_sizes, int n_in,
                              void* d_out, int out_size, void* d_ws, size_t ws_size,
                              hipStream_t stream)
{
    const float* image   = (const float*)d_in[0];
    const float* corners = (const float*)d_in[1];
    const float* W0      = (const float*)d_in[2];
    const float* b0      = (const float*)d_in[3];
    const float* W1      = (const float*)d_in[4];
    const float* b1      = (const float*)d_in[5];
    const float* W2      = (const float*)d_in[6];
    const float* b2      = (const float*)d_in[7];
    const float* Wf      = (const float*)d_in[8];
    const float* bf      = (const float*)d_in[9];
    const float* Wp      = (const float*)d_in[10];
    const float* bp      = (const float*)d_in[11];
    float* out = (float*)d_out;

    // workspace layout (256B-aligned), ~21.8 MB used
    char* w = (char*)d_ws;
    double* el2loc  = (double*)(w);                  //   262144 B
    double* partial = (double*)(w + 262144);         //     1024 B
    float2* pts     = (float2*)(w + 263168);         //   262144 B
    int*    ridx    = (int*)   (w + 525312);         //   131072 B
    float*  pmax    = (float*) (w + 656384);         //    34048 B
    float*  Wt      = (float*) (w + 690432);         //   147456 B
    float*  imgT    = (float*) (w + 837888);         // 16777216 B
    float*  Y0      = (float*) (w + 17615104);       //  4210688 B -> 21825792

    prep_scan_k <<<128, 256, 0, stream>>>(corners, el2loc, partial);
    prep_rest_k <<<PREST_GRID, 256, 0, stream>>>(corners, W0, W1, W2, image,
                                                 el2loc, partial, pts, ridx, Wt, imgT);
    convA2_k    <<<256, 256, 0, stream>>>(pts, ridx, imgT, Wt, b0, Y0);
    convBC_k    <<<NBC, 256, 0, stream>>>(Y0, Wt + 12288, b1, Wt + 24576, b2, pmax);
    fc_k        <<<1, 64, 0, stream>>>(pmax, Wf, bf, Wp, bp, out);
}